// Round 3
// baseline (85.190 us; speedup 1.0000x reference)
//
#include <hip/hip_runtime.h>

#define BATCH  8
#define NPTS   4096
#define NSLICE 32                 // target-set split per (dir,b)
#define SLICE  (NPTS / NSLICE)    // 128 targets per block
#define TPB1   512                // 8 waves/block, 2 blocks/CU
#define QPT    8                  // queries per thread (4096 / 512)
#define BIAS   1000.0f            // makes e positive -> uint-ordered atomicMin

// Stage 1: grid = 2 dirs x 8 batches x 32 target-slices = 512 blocks.
// Each thread holds 8 queries in NAMED registers; block stages its
// 128-target slice in LDS packed as (-2y0,-2y1,-2y2,||y||^2).
// Inner loop: 1 broadcast ds_read_b128 feeds 8x(3 fma + 1 min) = 32 VALU.
__global__ __launch_bounds__(TPB1, 4) void chamfer_stage1(
    const float* __restrict__ preds,
    const float* __restrict__ gts,
    unsigned int* __restrict__ umin)
{
    const int blk   = blockIdx.x;
    const int slice = blk % NSLICE;
    const int db    = blk / NSLICE;    // dir*8 + b
    const int dir   = db >> 3;
    const int b     = db & 7;

    const float* Q = dir ? gts   : preds;   // query set
    const float* T = dir ? preds : gts;     // target set

    __shared__ float4 sT[SLICE];            // 2 KiB

    const float* Tb = T + ((size_t)b * NPTS + slice * SLICE) * 3;
    if (threadIdx.x < SLICE) {
        const int j = threadIdx.x;
        const float y0 = Tb[j * 3 + 0];
        const float y1 = Tb[j * 3 + 1];
        const float y2 = Tb[j * 3 + 2];
        sT[j] = make_float4(-2.0f * y0, -2.0f * y1, -2.0f * y2,
                            y0 * y0 + y1 * y1 + y2 * y2);
    }

    // Load this thread's 8 consecutive queries (24 floats = 6 float4)
    // into NAMED float4s, then unpack with compile-time selects.
    // (A float[24] staging array + reinterpret_cast defeats SROA -> scratch.)
    const int q0 = threadIdx.x * QPT;
    const float4* p4 = reinterpret_cast<const float4*>(
        Q + ((size_t)b * NPTS + q0) * 3);
    const float4 v0 = p4[0], v1 = p4[1], v2 = p4[2];
    const float4 v3 = p4[3], v4 = p4[4], v5 = p4[5];

    float qx[QPT], qy[QPT], qz[QPT];
    qx[0] = v0.x; qy[0] = v0.y; qz[0] = v0.z;
    qx[1] = v0.w; qy[1] = v1.x; qz[1] = v1.y;
    qx[2] = v1.z; qy[2] = v1.w; qz[2] = v2.x;
    qx[3] = v2.y; qy[3] = v2.z; qz[3] = v2.w;
    qx[4] = v3.x; qy[4] = v3.y; qz[4] = v3.z;
    qx[5] = v3.w; qy[5] = v4.x; qz[5] = v4.y;
    qx[6] = v4.z; qy[6] = v4.w; qz[6] = v5.x;
    qx[7] = v5.y; qy[7] = v5.z; qz[7] = v5.w;

    __syncthreads();

    float m[QPT];
    #pragma unroll
    for (int k = 0; k < QPT; ++k) m[k] = 3.4e38f;

    #pragma unroll 4
    for (int j = 0; j < SLICE; ++j) {
        const float4 y = sT[j];
        #pragma unroll
        for (int k = 0; k < QPT; ++k) {
            // e = ||q-y||^2 - ||q||^2 = ry - 2*dot  (rx added in stage 2)
            const float e = fmaf(qx[k], y.x,
                             fmaf(qy[k], y.y,
                              fmaf(qz[k], y.z, y.w)));
            m[k] = fminf(m[k], e);
        }
    }

    // Combine partial mins across the 32 slices via uint atomicMin
    // (e + BIAS > 0, so the float bit pattern is uint-order-preserving).
    unsigned int* base = umin + (size_t)db * NPTS + q0;
    #pragma unroll
    for (int k = 0; k < QPT; ++k) {
        atomicMin(&base[k], __float_as_uint(m[k] + BIAS));
    }
}

// Stage 2: one thread per query; unbias, add rx, block-reduce, atomicAdd.
#define TPB2 256
__global__ __launch_bounds__(TPB2) void chamfer_stage2(
    const float* __restrict__ preds,
    const float* __restrict__ gts,
    const unsigned int* __restrict__ umin,
    float* __restrict__ out)
{
    const int g   = blockIdx.x * TPB2 + threadIdx.x;   // [0, 2*8*4096)
    const int db  = g >> 12;
    const int dir = db >> 3;
    const float* Q = dir ? gts : preds;
    const int bq  = ((db & 7) << 12) | (g & (NPTS - 1));

    const float x0 = Q[bq * 3 + 0];
    const float x1 = Q[bq * 3 + 1];
    const float x2 = Q[bq * 3 + 2];
    const float rx = x0 * x0 + x1 * x1 + x2 * x2;

    float s = (__uint_as_float(umin[g]) - BIAS) + rx;

    #pragma unroll
    for (int off = 32; off > 0; off >>= 1)
        s += __shfl_down(s, off, 64);

    __shared__ float red[TPB2 / 64];
    const int lane = threadIdx.x & 63;
    const int wid  = threadIdx.x >> 6;
    if (lane == 0) red[wid] = s;
    __syncthreads();
    if (threadIdx.x == 0) {
        float t = 0.0f;
        #pragma unroll
        for (int w = 0; w < TPB2 / 64; ++w) t += red[w];
        atomicAdd(out, t);
    }
}

extern "C" void kernel_launch(void* const* d_in, const int* in_sizes, int n_in,
                              void* d_out, int out_size, void* d_ws, size_t ws_size,
                              hipStream_t stream) {
    const float* preds = (const float*)d_in[0];
    const float* gts   = (const float*)d_in[1];
    float* out = (float*)d_out;
    unsigned int* umin = (unsigned int*)d_ws;   // 2*8*4096 uints = 256 KiB

    const size_t umin_bytes = (size_t)2 * BATCH * NPTS * sizeof(unsigned int);
    hipMemsetAsync(umin, 0xFF, umin_bytes, stream);   // uint max sentinel
    hipMemsetAsync(out, 0, sizeof(float), stream);

    chamfer_stage1<<<dim3(2 * BATCH * NSLICE), TPB1, 0, stream>>>(preds, gts, umin);
    chamfer_stage2<<<dim3(2 * BATCH * NPTS / TPB2), TPB2, 0, stream>>>(preds, gts, umin, out);
}